// Round 2
// baseline (5834.108 us; speedup 1.0000x reference)
//
#include <hip/hip_runtime.h>
#include <hip/hip_bf16.h>

#define Hdim 1024
#define Bsz  64
#define TST  127
#define NWG  128
#define NTHR 256
#define NCLS 50000

typedef __attribute__((ext_vector_type(8))) short s8v;   // 8 x bf16 fragment
typedef __attribute__((ext_vector_type(4))) float f4v;   // MFMA accumulator

// ---- workspace layout (bytes) ----
#define OFF_X0   0ull
#define SZ_X0    ((unsigned long long)TST * Bsz * Hdim * 4ull)   // 33,292,288
#define OFF_HB   (OFF_X0 + SZ_X0)                                // bf16 [64*1024]
#define OFF_N1   (OFF_HB  + 131072ull)
#define OFF_N3   (OFF_N1  + 131072ull)
#define OFF_N5   (OFF_N3  + 131072ull)
#define OFF_N2B  (OFF_N5  + 131072ull)                           // bf16 leaves
#define OFF_N4B  (OFF_N2B + 131072ull)
#define OFF_W0B  (OFF_N4B + 131072ull)                           // bf16 W0 [1024*1024]
#define OFF_BAR  (OFF_W0B + 2097152ull)                          // flags[128] u32
#define WS_NEED  (OFF_BAR + 1024ull)

__device__ __forceinline__ unsigned short f2b(float f) {
  union { float f; unsigned u; } v; v.f = f;
  return (unsigned short)((v.u + 0x7FFFu + ((v.u >> 16) & 1u)) >> 16);  // RNE
}
__device__ __forceinline__ float b2f(unsigned short u) {
  union { unsigned u; float f; } v; v.u = ((unsigned)u) << 16;
  return v.f;
}
__device__ __forceinline__ float fast_tanh(float x) {
  return 1.f - 2.f / (__expf(2.f * x) + 1.f);
}
__device__ __forceinline__ float fast_sigm(float x) {
  return 1.f / (1.f + __expf(-x));
}
__device__ __forceinline__ s8v pack8(const float* __restrict__ p) {
  s8v r;
#pragma unroll
  for (int i = 0; i < 8; ++i) r[i] = (short)f2b(p[i]);
  return r;
}

// write-through stores: land at the coherence point (L3), leave L2 clean so
// barriers need no wbl2 and consumer-side buffer_inv refetches are cheap.
__device__ __forceinline__ void st_sc16(unsigned short* p, unsigned short v) {
  asm volatile("global_store_short %0, %1, off sc0 sc1"
               :: "v"(p), "v"((unsigned)v) : "memory");
}
__device__ __forceinline__ void st_sc32(unsigned* p, unsigned v) {
  asm volatile("global_store_dword %0, %1, off sc0 sc1"
               :: "v"(p), "v"(v) : "memory");
}

// ---------------- W0 fp32 -> bf16 ----------------
__global__ __launch_bounds__(256) void k_cvt(const float* __restrict__ src,
                                             unsigned short* __restrict__ dst) {
  const int i = (blockIdx.x * 256 + threadIdx.x) * 4;
  float4 v = *(const float4*)(src + i);
  ushort4 o; o.x = f2b(v.x); o.y = f2b(v.y); o.z = f2b(v.z); o.w = f2b(v.w);
  *(ushort4*)(dst + i) = o;
}

// ---------------- X0[t] = emb[idx[:,t+1]] @ W0^T + b0 + bs0 ----------------
__global__ __launch_bounds__(256) void k_x0(const float* __restrict__ emb,
                                            const int* __restrict__ ids,
                                            const unsigned short* __restrict__ w0b,
                                            const float* __restrict__ b0,
                                            const float* __restrict__ bs,
                                            float* __restrict__ x0) {
  const int t  = blockIdx.x;            // 0..126
  const int cb = blockIdx.y * 256;      // column base
  const int lane = threadIdx.x & 63, wvv = threadIdx.x >> 6;
  const int lc = lane & 15, lg = lane >> 4;
  const int cw = cb + wvv * 64;
  const float* erow[4];
#pragma unroll
  for (int rt = 0; rt < 4; ++rt)
    erow[rt] = emb + (size_t)ids[(rt * 16 + lc) * 128 + t + 1] * Hdim + lg * 8;
  f4v acc[4][4];
#pragma unroll
  for (int rt = 0; rt < 4; ++rt)
#pragma unroll
    for (int ct = 0; ct < 4; ++ct) acc[rt][ct] = (f4v){0.f, 0.f, 0.f, 0.f};

  for (int ks = 0; ks < 32; ++ks) {
    s8v a[4];
#pragma unroll
    for (int rt = 0; rt < 4; ++rt) a[rt] = pack8(erow[rt] + ks * 32);
#pragma unroll
    for (int ct = 0; ct < 4; ++ct) {
      s8v b = *(const s8v*)(w0b + (size_t)(cw + ct * 16 + lc) * Hdim + ks * 32 + lg * 8);
#pragma unroll
      for (int rt = 0; rt < 4; ++rt)
        acc[rt][ct] = __builtin_amdgcn_mfma_f32_16x16x32_bf16(a[rt], b, acc[rt][ct], 0, 0, 0);
    }
  }
  float* xt = x0 + (size_t)t * (Bsz * Hdim);
#pragma unroll
  for (int ct = 0; ct < 4; ++ct) {
    const int col = cw + ct * 16 + lc;
    const float bias = b0[col] + bs[col];   // bs row 0
#pragma unroll
    for (int rt = 0; rt < 4; ++rt)
#pragma unroll
      for (int j = 0; j < 4; ++j)
        xt[(rt * 16 + lg * 4 + j) * Hdim + col] = acc[rt][ct][j] + bias;
  }
}

// ---------------- flag-array grid barrier ----------------
// WG w publishes flags[w]=phase (release; prior sc0sc1 stores already drained by
// the vmcnt(0) the compiler emits before s_barrier). Wave 0 polls all 128 flags
// (2 per lane, one u64 agent-load each) -> concurrent detection, no RMW chain.
__device__ __forceinline__ void gbar(unsigned* flags, int wg, unsigned phase) {
  __syncthreads();
  if (threadIdx.x == 0)
    __hip_atomic_store(&flags[wg], phase, __ATOMIC_RELEASE, __HIP_MEMORY_SCOPE_AGENT);
  if (threadIdx.x < 64) {
    const unsigned long long* fp = (const unsigned long long*)flags + threadIdx.x;
    for (;;) {
      unsigned long long v = __hip_atomic_load(fp, __ATOMIC_RELAXED, __HIP_MEMORY_SCOPE_AGENT);
      int ok = ((unsigned)v >= phase) & ((unsigned)(v >> 32) >= phase);
      if (__all(ok)) break;
      __builtin_amdgcn_s_sleep(1);
    }
  }
  __builtin_amdgcn_fence(__ATOMIC_ACQUIRE, "agent");   // inv L1/L2 -> fresh reads
  __syncthreads();
}

// out[64,16] slab = in[64,1024] @ Wslice^T, weights in LDS tiled [K/8][16][8]
__device__ __forceinline__ f4v slice_mm(const unsigned short* __restrict__ in_b,
                                        const unsigned short* ldw,
                                        int lc, int lg, int wvv) {
  f4v acc = (f4v){0.f, 0.f, 0.f, 0.f};
  const unsigned short* ar = in_b + (wvv * 16 + lc) * Hdim + lg * 8;
  const unsigned short* br = ldw + lg * 128 + lc * 8;
#pragma unroll 8
  for (int ks = 0; ks < 32; ++ks) {
    s8v a = *(const s8v*)(ar + ks * 32);
    s8v b = *(const s8v*)(br + ks * 512);
    acc = __builtin_amdgcn_mfma_f32_16x16x32_bf16(a, b, acc, 0, 0, 0);
  }
  return acc;
}

// ---------------- persistent scan: 127 steps x 4 levels ----------------
__global__ __launch_bounds__(256, 1) void k_scan(const float* __restrict__ Ws,
                                                 const float* __restrict__ bs,
                                                 const float* __restrict__ h_in,
                                                 const float* __restrict__ Wsum,
                                                 const float* __restrict__ bsum,
                                                 const float* __restrict__ act,
                                                 char* __restrict__ ws) {
  __shared__ unsigned short lds[3 * 16384];   // 96 KiB: three [1024 x 16] slices
  const int w = blockIdx.x;
  const int half = w >> 6;          // 0: {M0,M1,M3}, 1: {M2,M4,M5}
  const int c0 = (w & 63) * 16;
  const int tid = threadIdx.x;
  const int lane = tid & 63, wvv = tid >> 6;
  const int lc = lane & 15, lg = lane >> 4;

  unsigned short* hb  = (unsigned short*)(ws + OFF_HB);
  unsigned short* n1b = (unsigned short*)(ws + OFF_N1);
  unsigned short* n3b = (unsigned short*)(ws + OFF_N3);
  unsigned short* n5b = (unsigned short*)(ws + OFF_N5);
  unsigned short* n2b = (unsigned short*)(ws + OFF_N2B);
  unsigned short* n4b = (unsigned short*)(ws + OFF_N4B);
  const float* x0 = (const float*)(ws + OFF_X0);
  unsigned* flags = (unsigned*)(ws + OFF_BAR);

  // load 3 weight slices (fp32 global -> bf16 LDS, tiled [k/8][16][8])
  const int m0 = (half == 0) ? 0 : 2;
  const int m1 = (half == 0) ? 1 : 4;
  const int m2 = (half == 0) ? 3 : 5;
  const int mats[3] = {m0, m1, m2};
#pragma unroll
  for (int s = 0; s < 3; ++s) {
    const float* msrc = Ws + (size_t)mats[s] * (Hdim * Hdim);
    unsigned short* dst = lds + s * 16384;
    for (int i = tid; i < 4096; i += NTHR) {
      const int c = i >> 8, k4 = i & 255;
      float4 v = *(const float4*)(msrc + (size_t)(c0 + c) * Hdim + k4 * 4);
      ushort4 o; o.x = f2b(v.x); o.y = f2b(v.y); o.z = f2b(v.z); o.w = f2b(v.w);
      *(ushort4*)(dst + ((k4 >> 1) * 16 + c) * 8 + (k4 & 1) * 4) = o;
    }
  }
  // per-lane biases for this WG's columns
  float bias_a, bias_b, bias_c = 0.f;
  if (half == 0) { bias_a = bs[1 * Hdim + c0 + lc]; bias_b = bs[3 * Hdim + c0 + lc]; }
  else { bias_a = bs[2 * Hdim + c0 + lc]; bias_b = bs[4 * Hdim + c0 + lc]; bias_c = bs[5 * Hdim + c0 + lc]; }

  // softmax combine weights over nodes {2,4,6} -> weight rows {1,3,5}
  float cw[3];
#pragma unroll
  for (int j = 0; j < 3; ++j) {
    const int i = 2 * j + 1;
    float s = bsum[i];
    for (int a2 = 0; a2 < 12; ++a2) s += Wsum[i * 12 + a2] * act[a2];
    cw[j] = s;
  }
  {
    float m = fmaxf(cw[0], fmaxf(cw[1], cw[2]));
    float e0 = __expf(cw[0] - m), e1 = __expf(cw[1] - m), e2 = __expf(cw[2] - m);
    float inv = 1.f / (e0 + e1 + e2);
    cw[0] = e0 * inv; cw[1] = e1 * inv; cw[2] = e2 * inv;
  }

  // initial h fp32 -> bf16 (write-through)
  {
    const int base = w * 512 + tid * 2;
    unsigned pk = (unsigned)f2b(h_in[base]) | ((unsigned)f2b(h_in[base + 1]) << 16);
    st_sc32((unsigned*)(hb + base), pk);
  }

  unsigned phase = 1;
  gbar(flags, w, phase++);

  for (int t = 0; t < TST; ++t) {
    // L1: n1 = tanh(h @ M0^T + X0[t])   (X0 already contains b0+bs0)
    if (half == 0) {
      f4v acc = slice_mm(hb, lds, lc, lg, wvv);
      const float* xt = x0 + (size_t)t * (Bsz * Hdim);
#pragma unroll
      for (int j = 0; j < 4; ++j) {
        const int row = wvv * 16 + lg * 4 + j;
        st_sc16(n1b + row * Hdim + c0 + lc,
                f2b(fast_tanh(acc[j] + xt[row * Hdim + c0 + lc])));
      }
    }
    gbar(flags, w, phase++);

    // L2: n2 = relu(n1@M1^T+b1) [half0] ; n3 = sigmoid(n1@M2^T+b2) [half1]
    if (half == 0) {
      f4v acc = slice_mm(n1b, lds + 16384, lc, lg, wvv);
#pragma unroll
      for (int j = 0; j < 4; ++j) {
        const int row = wvv * 16 + lg * 4 + j;
        st_sc16(n2b + row * Hdim + c0 + lc, f2b(fmaxf(acc[j] + bias_a, 0.f)));
      }
    } else {
      f4v acc = slice_mm(n1b, lds, lc, lg, wvv);
#pragma unroll
      for (int j = 0; j < 4; ++j) {
        const int row = wvv * 16 + lg * 4 + j;
        st_sc16(n3b + row * Hdim + c0 + lc, f2b(fast_sigm(acc[j] + bias_a)));
      }
    }
    gbar(flags, w, phase++);

    // L3: n4 = tanh(n3@M3^T+b3) [half0] ; n5 = relu(n3@M4^T+b4) [half1]
    if (half == 0) {
      f4v acc = slice_mm(n3b, lds + 32768, lc, lg, wvv);
#pragma unroll
      for (int j = 0; j < 4; ++j) {
        const int row = wvv * 16 + lg * 4 + j;
        st_sc16(n4b + row * Hdim + c0 + lc, f2b(fast_tanh(acc[j] + bias_b)));
      }
    } else {
      f4v acc = slice_mm(n3b, lds + 16384, lc, lg, wvv);
#pragma unroll
      for (int j = 0; j < 4; ++j) {
        const int row = wvv * 16 + lg * 4 + j;
        st_sc16(n5b + row * Hdim + c0 + lc, f2b(fmaxf(acc[j] + bias_b, 0.f)));
      }
    }
    gbar(flags, w, phase++);

    // L4: n6 = tanh(n5@M5^T+b5); h = cw0*n2 + cw1*n4 + cw2*n6  [half1]
    if (half == 1) {
      f4v acc = slice_mm(n5b, lds + 32768, lc, lg, wvv);
#pragma unroll
      for (int j = 0; j < 4; ++j) {
        const int row = wvv * 16 + lg * 4 + j;
        const int col = c0 + lc;
        const float v6 = fast_tanh(acc[j] + bias_c);
        const float hv = cw[0] * b2f(n2b[row * Hdim + col]) +
                         cw[1] * b2f(n4b[row * Hdim + col]) + cw[2] * v6;
        st_sc16(hb + row * Hdim + col, f2b(hv));
      }
    }
    gbar(flags, w, phase++);
  }
}

// ---------------- epilogue: out = h @ W_out^T + b_out ----------------
__global__ __launch_bounds__(256) void k_out(const unsigned short* __restrict__ hb,
                                             const float* __restrict__ wout,
                                             const float* __restrict__ bout,
                                             float* __restrict__ out) {
  const int cb = blockIdx.x * 128;
  const int lane = threadIdx.x & 63, wvv = threadIdx.x >> 6;
  const int lc = lane & 15, lg = lane >> 4;
  const int cw = cb + wvv * 32;
  f4v acc[4][2];
#pragma unroll
  for (int rt = 0; rt < 4; ++rt)
#pragma unroll
    for (int ct = 0; ct < 2; ++ct) acc[rt][ct] = (f4v){0.f, 0.f, 0.f, 0.f};

  for (int ks = 0; ks < 32; ++ks) {
    s8v a[4];
#pragma unroll
    for (int rt = 0; rt < 4; ++rt)
      a[rt] = *(const s8v*)(hb + (rt * 16 + lc) * Hdim + ks * 32 + lg * 8);
#pragma unroll
    for (int ct = 0; ct < 2; ++ct) {
      const int col = cw + ct * 16 + lc;
      const int cs = col < NCLS ? col : NCLS - 1;
      s8v b = pack8(wout + (size_t)cs * Hdim + ks * 32 + lg * 8);
#pragma unroll
      for (int rt = 0; rt < 4; ++rt)
        acc[rt][ct] = __builtin_amdgcn_mfma_f32_16x16x32_bf16(a[rt], b, acc[rt][ct], 0, 0, 0);
    }
  }
#pragma unroll
  for (int ct = 0; ct < 2; ++ct) {
    const int col = cw + ct * 16 + lc;
    if (col < NCLS) {
      const float bias = bout[col];
#pragma unroll
      for (int rt = 0; rt < 4; ++rt)
#pragma unroll
        for (int j = 0; j < 4; ++j)
          out[(size_t)(rt * 16 + lg * 4 + j) * NCLS + col] = acc[rt][ct][j] + bias;
    }
  }
}

extern "C" void kernel_launch(void* const* d_in, const int* in_sizes, int n_in,
                              void* d_out, int out_size, void* d_ws, size_t ws_size,
                              hipStream_t stream) {
  (void)in_sizes; (void)n_in; (void)out_size;
  if (ws_size < WS_NEED) return;

  const float* emb  = (const float*)d_in[0];
  const float* h0   = (const float*)d_in[1];
  const int*   ids  = (const int*)d_in[2];
  const float* W0   = (const float*)d_in[3];
  const float* b0   = (const float*)d_in[4];
  const float* Ws   = (const float*)d_in[5];
  const float* bsp  = (const float*)d_in[6];
  const float* Wout = (const float*)d_in[7];
  const float* bout = (const float*)d_in[8];
  const float* Wsum = (const float*)d_in[9];
  const float* bsum = (const float*)d_in[10];
  const float* act  = (const float*)d_in[11];
  char* ws  = (char*)d_ws;
  float* out = (float*)d_out;

  hipMemsetAsync(ws + OFF_BAR, 0, 1024, stream);                      // flags
  k_cvt<<<1024, 256, 0, stream>>>(W0, (unsigned short*)(ws + OFF_W0B));
  k_x0<<<dim3(TST, 4), 256, 0, stream>>>(emb, ids, (const unsigned short*)(ws + OFF_W0B),
                                         b0, bsp, (float*)(ws + OFF_X0));

  void* args[] = { (void*)&Ws, (void*)&bsp, (void*)&h0, (void*)&Wsum,
                   (void*)&bsum, (void*)&act, (void*)&ws };
  hipLaunchCooperativeKernel((void*)k_scan, dim3(NWG), dim3(NTHR), args, 0, stream);

  k_out<<<391, 256, 0, stream>>>((const unsigned short*)(ws + OFF_HB), Wout, bout, out);
}

// Round 4
// 4397.409 us; speedup vs baseline: 1.3267x; 1.3267x over previous
//
#include <hip/hip_runtime.h>
#include <hip/hip_bf16.h>

#define Hdim 1024
#define Bsz  64
#define TST  127
#define NWG  128
#define NTHR 256
#define NCLS 50000

typedef __attribute__((ext_vector_type(8))) short s8v;       // 8 x bf16 fragment
typedef __attribute__((ext_vector_type(4))) float f4v;       // MFMA accumulator
typedef __attribute__((ext_vector_type(2))) unsigned u2v;    // packed 4 x bf16

// ---- workspace layout (bytes) ----
#define OFF_X0   0ull
#define SZ_X0    ((unsigned long long)TST * Bsz * Hdim * 4ull)   // 33,292,288
#define OFF_HB   (OFF_X0 + SZ_X0)                                // bf16 [64*1024]
#define OFF_N1   (OFF_HB  + 131072ull)
#define OFF_N3   (OFF_N1  + 131072ull)
#define OFF_N5   (OFF_N3  + 131072ull)
#define OFF_N2B  (OFF_N5  + 131072ull)                           // bf16 leaves
#define OFF_N4B  (OFF_N2B + 131072ull)
#define OFF_W0B  (OFF_N4B + 131072ull)                           // bf16 W0 [1024*1024]
#define OFF_BAR  (OFF_W0B + 2097152ull)                          // flags[128] u32
#define WS_NEED  (OFF_BAR + 1024ull)

__device__ __forceinline__ unsigned short f2b(float f) {
  union { float f; unsigned u; } v; v.f = f;
  return (unsigned short)((v.u + 0x7FFFu + ((v.u >> 16) & 1u)) >> 16);  // RNE
}
__device__ __forceinline__ float b2f(unsigned short u) {
  union { unsigned u; float f; } v; v.u = ((unsigned)u) << 16;
  return v.f;
}
__device__ __forceinline__ float fast_tanh(float x) {
  return 1.f - 2.f / (__expf(2.f * x) + 1.f);
}
__device__ __forceinline__ float fast_sigm(float x) {
  return 1.f / (1.f + __expf(-x));
}
__device__ __forceinline__ s8v pack8(const float* __restrict__ p) {
  s8v r;
#pragma unroll
  for (int i = 0; i < 8; ++i) r[i] = (short)f2b(p[i]);
  return r;
}

// ---- coherent (L3-direct) helpers: sc0 sc1 = bypass L1+L2 ----
__device__ __forceinline__ void st_sc32(unsigned* p, unsigned v) {
  asm volatile("global_store_dword %0, %1, off sc0 sc1" :: "v"(p), "v"(v) : "memory");
}
__device__ __forceinline__ void st_sc64(unsigned short* p, u2v v) {
  asm volatile("global_store_dwordx2 %0, %1, off sc0 sc1" :: "v"(p), "v"(v) : "memory");
}
__device__ __forceinline__ void wait_vm0() {
  asm volatile("s_waitcnt vmcnt(0)" ::: "memory");
}
__device__ __forceinline__ void st_bf4(unsigned short* p, float x0, float x1, float x2, float x3) {
  u2v v;
  v[0] = (unsigned)f2b(x0) | ((unsigned)f2b(x1) << 16);
  v[1] = (unsigned)f2b(x2) | ((unsigned)f2b(x3) << 16);
  st_sc64(p, v);
}

// 16 coherent dwordx4 loads + the waitcnt in ONE asm block: no window where the
// compiler can spill/copy an in-flight destination register (the R3 bug).
#define GL16(B, P) asm volatile(                                        \
  "global_load_dwordx4 %0,  %16, off sc0 sc1\n\t"                       \
  "global_load_dwordx4 %1,  %16, off offset:64 sc0 sc1\n\t"             \
  "global_load_dwordx4 %2,  %16, off offset:128 sc0 sc1\n\t"            \
  "global_load_dwordx4 %3,  %16, off offset:192 sc0 sc1\n\t"            \
  "global_load_dwordx4 %4,  %16, off offset:256 sc0 sc1\n\t"            \
  "global_load_dwordx4 %5,  %16, off offset:320 sc0 sc1\n\t"            \
  "global_load_dwordx4 %6,  %16, off offset:384 sc0 sc1\n\t"            \
  "global_load_dwordx4 %7,  %16, off offset:448 sc0 sc1\n\t"            \
  "global_load_dwordx4 %8,  %16, off offset:512 sc0 sc1\n\t"            \
  "global_load_dwordx4 %9,  %16, off offset:576 sc0 sc1\n\t"            \
  "global_load_dwordx4 %10, %16, off offset:640 sc0 sc1\n\t"            \
  "global_load_dwordx4 %11, %16, off offset:704 sc0 sc1\n\t"            \
  "global_load_dwordx4 %12, %16, off offset:768 sc0 sc1\n\t"            \
  "global_load_dwordx4 %13, %16, off offset:832 sc0 sc1\n\t"            \
  "global_load_dwordx4 %14, %16, off offset:896 sc0 sc1\n\t"            \
  "global_load_dwordx4 %15, %16, off offset:960 sc0 sc1\n\t"            \
  "s_waitcnt vmcnt(0)"                                                  \
  : "=&v"(B[0]), "=&v"(B[1]), "=&v"(B[2]), "=&v"(B[3]),                 \
    "=&v"(B[4]), "=&v"(B[5]), "=&v"(B[6]), "=&v"(B[7]),                 \
    "=&v"(B[8]), "=&v"(B[9]), "=&v"(B[10]), "=&v"(B[11]),               \
    "=&v"(B[12]), "=&v"(B[13]), "=&v"(B[14]), "=&v"(B[15])              \
  : "v"(P) : "memory")

// ---------------- W0 fp32 -> bf16 ----------------
__global__ __launch_bounds__(256) void k_cvt(const float* __restrict__ src,
                                             unsigned short* __restrict__ dst) {
  const int i = (blockIdx.x * 256 + threadIdx.x) * 4;
  float4 v = *(const float4*)(src + i);
  ushort4 o; o.x = f2b(v.x); o.y = f2b(v.y); o.z = f2b(v.z); o.w = f2b(v.w);
  *(ushort4*)(dst + i) = o;
}

// ---------------- X0[t] = emb[idx[:,t+1]] @ W0^T + b0 + bs0 ----------------
__global__ __launch_bounds__(256) void k_x0(const float* __restrict__ emb,
                                            const int* __restrict__ ids,
                                            const unsigned short* __restrict__ w0b,
                                            const float* __restrict__ b0,
                                            const float* __restrict__ bs,
                                            float* __restrict__ x0) {
  const int t  = blockIdx.x;            // 0..126
  const int cb = blockIdx.y * 256;      // column base
  const int lane = threadIdx.x & 63, wvv = threadIdx.x >> 6;
  const int lc = lane & 15, lg = lane >> 4;
  const int cw = cb + wvv * 64;
  const float* erow[4];
#pragma unroll
  for (int rt = 0; rt < 4; ++rt)
    erow[rt] = emb + (size_t)ids[(rt * 16 + lc) * 128 + t + 1] * Hdim + lg * 8;
  f4v acc[4][4];
#pragma unroll
  for (int rt = 0; rt < 4; ++rt)
#pragma unroll
    for (int ct = 0; ct < 4; ++ct) acc[rt][ct] = (f4v){0.f, 0.f, 0.f, 0.f};

  for (int ks = 0; ks < 32; ++ks) {
    s8v a[4];
#pragma unroll
    for (int rt = 0; rt < 4; ++rt) a[rt] = pack8(erow[rt] + ks * 32);
#pragma unroll
    for (int ct = 0; ct < 4; ++ct) {
      s8v b = *(const s8v*)(w0b + (size_t)(cw + ct * 16 + lc) * Hdim + ks * 32 + lg * 8);
#pragma unroll
      for (int rt = 0; rt < 4; ++rt)
        acc[rt][ct] = __builtin_amdgcn_mfma_f32_16x16x32_bf16(a[rt], b, acc[rt][ct], 0, 0, 0);
    }
  }
  float* xt = x0 + (size_t)t * (Bsz * Hdim);
#pragma unroll
  for (int ct = 0; ct < 4; ++ct) {
    const int col = cw + ct * 16 + lc;
    const float bias = b0[col] + bs[col];   // bs row 0
#pragma unroll
    for (int rt = 0; rt < 4; ++rt)
#pragma unroll
      for (int j = 0; j < 4; ++j)
        xt[(rt * 16 + lg * 4 + j) * Hdim + col] = acc[rt][ct][j] + bias;
  }
}

// ---------------- grid barrier: coherent flag array, tight spin ----------------
// Caller guarantees its data stores are drained (wait_vm0 after stores).
__device__ __forceinline__ void gbar(unsigned* flags, int wg, unsigned phase) {
  __syncthreads();
  const int tid = threadIdx.x;
  if (tid == 0) st_sc32(flags + wg, phase);
  if (tid < 64) {
    const unsigned long long* fp = (const unsigned long long*)flags + tid;
    for (;;) {
      unsigned long long v;
      asm volatile("global_load_dwordx2 %0, %1, off sc0 sc1\n\ts_waitcnt vmcnt(0)"
                   : "=v"(v) : "v"(fp) : "memory");
      int ok = ((unsigned)v >= phase) & ((unsigned)(v >> 32) >= phase);
      if (__all(ok)) break;              // tight spin: keeps clocks boosted
    }
  }
  __syncthreads();
}

// one 16-col x 16-row output tile per wave, transposed MFMA:
// D[c, r] = sum_k W[c0+c, k] * act[r, k] via mfma(A=W_frag, B=act_frag).
// lane (lc,lg): batch row = wvv*16+lc, weight cols = c0+lg*4+0..3.
__device__ __forceinline__ f4v slab_mm(const unsigned short* in_b,
                                       const unsigned short* ldw,
                                       int lc, int lg, int wvv) {
  const unsigned short* pa = in_b + (wvv * 16 + lc) * Hdim + lg * 8;
  const unsigned short* br = ldw + lg * 128 + lc * 8;
  f4v a0 = (f4v){0.f, 0.f, 0.f, 0.f}, a1 = (f4v){0.f, 0.f, 0.f, 0.f};
  s8v bb[16];

  GL16(bb, pa);                           // ks 0..15, drained in-block
  __builtin_amdgcn_sched_barrier(0);
#pragma unroll
  for (int k = 0; k < 16; k += 2) {
    s8v w0 = *(const s8v*)(br + k * 512);
    s8v w1 = *(const s8v*)(br + (k + 1) * 512);
    a0 = __builtin_amdgcn_mfma_f32_16x16x32_bf16(w0, bb[k], a0, 0, 0, 0);
    a1 = __builtin_amdgcn_mfma_f32_16x16x32_bf16(w1, bb[k + 1], a1, 0, 0, 0);
  }

  GL16(bb, pa + 512);                     // ks 16..31
  __builtin_amdgcn_sched_barrier(0);
#pragma unroll
  for (int k = 0; k < 16; k += 2) {
    s8v w0 = *(const s8v*)(br + (16 + k) * 512);
    s8v w1 = *(const s8v*)(br + (17 + k) * 512);
    a0 = __builtin_amdgcn_mfma_f32_16x16x32_bf16(w0, bb[k], a0, 0, 0, 0);
    a1 = __builtin_amdgcn_mfma_f32_16x16x32_bf16(w1, bb[k + 1], a1, 0, 0, 0);
  }
  return a0 + a1;
}

// ---------------- persistent scan: 127 steps x 4 levels ----------------
__global__ __launch_bounds__(256, 1) void k_scan(const float* __restrict__ Ws,
                                                 const float* __restrict__ bs,
                                                 const float* __restrict__ h_in,
                                                 const float* __restrict__ Wsum,
                                                 const float* __restrict__ bsum,
                                                 const float* __restrict__ act,
                                                 char* __restrict__ ws) {
  __shared__ unsigned short lds[3 * 16384];   // 96 KiB: three [16 cols x 1024 k] slices
  const int w = blockIdx.x;
  const int half = w >> 6;          // 0: {M0,M1,M3}, 1: {M2,M4,M5}
  const int c0 = (w & 63) * 16;
  const int tid = threadIdx.x;
  const int lane = tid & 63, wvv = tid >> 6;
  const int lc = lane & 15, lg = lane >> 4;

  unsigned short* hb  = (unsigned short*)(ws + OFF_HB);
  unsigned short* n1b = (unsigned short*)(ws + OFF_N1);
  unsigned short* n3b = (unsigned short*)(ws + OFF_N3);
  unsigned short* n5b = (unsigned short*)(ws + OFF_N5);
  unsigned short* n2b = (unsigned short*)(ws + OFF_N2B);
  unsigned short* n4b = (unsigned short*)(ws + OFF_N4B);
  const float* x0 = (const float*)(ws + OFF_X0);
  unsigned* flags = (unsigned*)(ws + OFF_BAR);

  // load 3 weight slices (fp32 global -> bf16 LDS, tiled [k/8][16][8])
  const int m0 = (half == 0) ? 0 : 2;
  const int m1 = (half == 0) ? 1 : 4;
  const int m2 = (half == 0) ? 3 : 5;
  const int mats[3] = {m0, m1, m2};
#pragma unroll
  for (int s = 0; s < 3; ++s) {
    const float* msrc = Ws + (size_t)mats[s] * (Hdim * Hdim);
    unsigned short* dst = lds + s * 16384;
    for (int i = tid; i < 4096; i += NTHR) {
      const int c = i >> 8, k4 = i & 255;
      float4 v = *(const float4*)(msrc + (size_t)(c0 + c) * Hdim + k4 * 4);
      ushort4 o; o.x = f2b(v.x); o.y = f2b(v.y); o.z = f2b(v.z); o.w = f2b(v.w);
      *(ushort4*)(dst + ((k4 >> 1) * 16 + c) * 8 + (k4 & 1) * 4) = o;
    }
  }
  // per-lane biases: 4 consecutive cols (c0 + lg*4 + 0..3) per matrix
  float4 bias_a, bias_b, bias_c = (float4){0.f, 0.f, 0.f, 0.f};
  if (half == 0) {
    bias_a = *(const float4*)(bs + 1 * Hdim + c0 + lg * 4);
    bias_b = *(const float4*)(bs + 3 * Hdim + c0 + lg * 4);
  } else {
    bias_a = *(const float4*)(bs + 2 * Hdim + c0 + lg * 4);
    bias_b = *(const float4*)(bs + 4 * Hdim + c0 + lg * 4);
    bias_c = *(const float4*)(bs + 5 * Hdim + c0 + lg * 4);
  }

  // softmax combine weights over nodes {2,4,6} -> weight rows {1,3,5}
  float cw[3];
#pragma unroll
  for (int j = 0; j < 3; ++j) {
    const int i = 2 * j + 1;
    float s = bsum[i];
    for (int a2 = 0; a2 < 12; ++a2) s += Wsum[i * 12 + a2] * act[a2];
    cw[j] = s;
  }
  {
    float m = fmaxf(cw[0], fmaxf(cw[1], cw[2]));
    float e0 = __expf(cw[0] - m), e1 = __expf(cw[1] - m), e2 = __expf(cw[2] - m);
    float inv = 1.f / (e0 + e1 + e2);
    cw[0] = e0 * inv; cw[1] = e1 * inv; cw[2] = e2 * inv;
  }

  // initial h fp32 -> bf16 (coherent)
  {
    const int base = w * 512 + tid * 2;
    unsigned pk = (unsigned)f2b(h_in[base]) | ((unsigned)f2b(h_in[base + 1]) << 16);
    st_sc32((unsigned*)(hb + base), pk);
    wait_vm0();
  }

  unsigned phase = 1;
  gbar(flags, w, phase++);

  const int row = wvv * 16 + lc;          // this lane's batch row
  const int colb = c0 + lg * 4;           // this lane's 4 output cols

  for (int t = 0; t < TST; ++t) {
    // L1: n1 = tanh(h @ M0^T + X0[t])   (X0 already contains b0+bs0)
    if (half == 0) {
      f4v acc = slab_mm(hb, lds, lc, lg, wvv);
      float4 xv = *(const float4*)(x0 + (size_t)t * (Bsz * Hdim) + row * Hdim + colb);
      st_bf4(n1b + row * Hdim + colb,
             fast_tanh(acc[0] + xv.x), fast_tanh(acc[1] + xv.y),
             fast_tanh(acc[2] + xv.z), fast_tanh(acc[3] + xv.w));
      wait_vm0();
    }
    gbar(flags, w, phase++);

    // L2: n2 = relu(n1@M1^T+b1) [half0] ; n3 = sigmoid(n1@M2^T+b2) [half1]
    if (half == 0) {
      f4v acc = slab_mm(n1b, lds + 16384, lc, lg, wvv);
      st_bf4(n2b + row * Hdim + colb,
             fmaxf(acc[0] + bias_a.x, 0.f), fmaxf(acc[1] + bias_a.y, 0.f),
             fmaxf(acc[2] + bias_a.z, 0.f), fmaxf(acc[3] + bias_a.w, 0.f));
    } else {
      f4v acc = slab_mm(n1b, lds, lc, lg, wvv);
      st_bf4(n3b + row * Hdim + colb,
             fast_sigm(acc[0] + bias_a.x), fast_sigm(acc[1] + bias_a.y),
             fast_sigm(acc[2] + bias_a.z), fast_sigm(acc[3] + bias_a.w));
    }
    wait_vm0();
    gbar(flags, w, phase++);

    // L3: n4 = tanh(n3@M3^T+b3) [half0] ; n5 = relu(n3@M4^T+b4) [half1]
    if (half == 0) {
      f4v acc = slab_mm(n3b, lds + 32768, lc, lg, wvv);
      st_bf4(n4b + row * Hdim + colb,
             fast_tanh(acc[0] + bias_b.x), fast_tanh(acc[1] + bias_b.y),
             fast_tanh(acc[2] + bias_b.z), fast_tanh(acc[3] + bias_b.w));
    } else {
      f4v acc = slab_mm(n3b, lds + 16384, lc, lg, wvv);
      st_bf4(n5b + row * Hdim + colb,
             fmaxf(acc[0] + bias_b.x, 0.f), fmaxf(acc[1] + bias_b.y, 0.f),
             fmaxf(acc[2] + bias_b.z, 0.f), fmaxf(acc[3] + bias_b.w, 0.f));
    }
    wait_vm0();
    gbar(flags, w, phase++);

    // L4: n6 = tanh(n5@M5^T+b5); h = cw0*n2 + cw1*n4 + cw2*n6  [half1]
    if (half == 1) {
      f4v acc = slab_mm(n5b, lds + 32768, lc, lg, wvv);
      u2v v2, v4;
      const unsigned short* p2 = n2b + row * Hdim + colb;
      const unsigned short* p4 = n4b + row * Hdim + colb;
      asm volatile("global_load_dwordx2 %0, %2, off sc0 sc1\n\t"
                   "global_load_dwordx2 %1, %3, off sc0 sc1\n\t"
                   "s_waitcnt vmcnt(0)"
                   : "=&v"(v2), "=&v"(v4) : "v"(p2), "v"(p4) : "memory");
      float hv[4];
#pragma unroll
      for (int j = 0; j < 4; ++j) {
        const float v6 = fast_tanh(acc[j] + ((const float*)&bias_c)[j]);
        const float f2 = b2f((unsigned short)(v2[j >> 1] >> ((j & 1) * 16)));
        const float f4 = b2f((unsigned short)(v4[j >> 1] >> ((j & 1) * 16)));
        hv[j] = cw[0] * f2 + cw[1] * f4 + cw[2] * v6;
      }
      st_bf4(hb + row * Hdim + colb, hv[0], hv[1], hv[2], hv[3]);
      wait_vm0();
    }
    gbar(flags, w, phase++);
  }
}

// ---------------- epilogue: out = h @ W_out^T + b_out ----------------
__global__ __launch_bounds__(256) void k_out(const unsigned short* __restrict__ hb,
                                             const float* __restrict__ wout,
                                             const float* __restrict__ bout,
                                             float* __restrict__ out) {
  const int cb = blockIdx.x * 128;
  const int lane = threadIdx.x & 63, wvv = threadIdx.x >> 6;
  const int lc = lane & 15, lg = lane >> 4;
  const int cw = cb + wvv * 32;
  f4v acc[4][2];
#pragma unroll
  for (int rt = 0; rt < 4; ++rt)
#pragma unroll
    for (int ct = 0; ct < 2; ++ct) acc[rt][ct] = (f4v){0.f, 0.f, 0.f, 0.f};

  for (int ks = 0; ks < 32; ++ks) {
    s8v a[4];
#pragma unroll
    for (int rt = 0; rt < 4; ++rt)
      a[rt] = *(const s8v*)(hb + (rt * 16 + lc) * Hdim + ks * 32 + lg * 8);
#pragma unroll
    for (int ct = 0; ct < 2; ++ct) {
      const int col = cw + ct * 16 + lc;
      const int cs = col < NCLS ? col : NCLS - 1;
      s8v b = pack8(wout + (size_t)cs * Hdim + ks * 32 + lg * 8);
#pragma unroll
      for (int rt = 0; rt < 4; ++rt)
        acc[rt][ct] = __builtin_amdgcn_mfma_f32_16x16x32_bf16(a[rt], b, acc[rt][ct], 0, 0, 0);
    }
  }
#pragma unroll
  for (int ct = 0; ct < 2; ++ct) {
    const int col = cw + ct * 16 + lc;
    if (col < NCLS) {
      const float bias = bout[col];
#pragma unroll
      for (int rt = 0; rt < 4; ++rt)
#pragma unroll
        for (int j = 0; j < 4; ++j)
          out[(size_t)(rt * 16 + lg * 4 + j) * NCLS + col] = acc[rt][ct][j] + bias;
    }
  }
}

extern "C" void kernel_launch(void* const* d_in, const int* in_sizes, int n_in,
                              void* d_out, int out_size, void* d_ws, size_t ws_size,
                              hipStream_t stream) {
  (void)in_sizes; (void)n_in; (void)out_size;
  if (ws_size < WS_NEED) return;

  const float* emb  = (const float*)d_in[0];
  const float* h0   = (const float*)d_in[1];
  const int*   ids  = (const int*)d_in[2];
  const float* W0   = (const float*)d_in[3];
  const float* b0   = (const float*)d_in[4];
  const float* Ws   = (const float*)d_in[5];
  const float* bsp  = (const float*)d_in[6];
  const float* Wout = (const float*)d_in[7];
  const float* bout = (const float*)d_in[8];
  const float* Wsum = (const float*)d_in[9];
  const float* bsum = (const float*)d_in[10];
  const float* act  = (const float*)d_in[11];
  char* ws  = (char*)d_ws;
  float* out = (float*)d_out;

  hipMemsetAsync(ws + OFF_BAR, 0, 1024, stream);                      // flags
  k_cvt<<<1024, 256, 0, stream>>>(W0, (unsigned short*)(ws + OFF_W0B));
  k_x0<<<dim3(TST, 4), 256, 0, stream>>>(emb, ids, (const unsigned short*)(ws + OFF_W0B),
                                         b0, bsp, (float*)(ws + OFF_X0));

  void* args[] = { (void*)&Ws, (void*)&bsp, (void*)&h0, (void*)&Wsum,
                   (void*)&bsum, (void*)&act, (void*)&ws };
  hipLaunchCooperativeKernel((void*)k_scan, dim3(NWG), dim3(NTHR), args, 0, stream);

  k_out<<<391, 256, 0, stream>>>((const unsigned short*)(ws + OFF_HB), Wout, bout, out);
}

// Round 6
// 4255.636 us; speedup vs baseline: 1.3709x; 1.0333x over previous
//
#include <hip/hip_runtime.h>
#include <hip/hip_bf16.h>

#define Hdim 1024
#define Bsz  64
#define TST  127
#define NWG  128
#define NGRID 192            // 128 workers + 64 clock-heater WGs
#define NTHR 256
#define NCLS 50000
#define FINPH ((unsigned)(4 * TST + 1))   // final flag value = 509

typedef __attribute__((ext_vector_type(8))) short s8v;       // 8 x bf16 fragment
typedef __attribute__((ext_vector_type(4))) float f4v;       // MFMA accumulator
typedef __attribute__((ext_vector_type(2))) unsigned u2v;    // packed 4 x bf16

// ---- workspace layout (bytes) ----
#define OFF_X0   0ull
#define SZ_X0    ((unsigned long long)TST * Bsz * Hdim * 4ull)   // 33,292,288
#define OFF_HB   (OFF_X0 + SZ_X0)                                // bf16 [64*1024]
#define OFF_N1   (OFF_HB  + 131072ull)
#define OFF_N3   (OFF_N1  + 131072ull)
#define OFF_N5   (OFF_N3  + 131072ull)
#define OFF_N2B  (OFF_N5  + 131072ull)                           // bf16 leaves
#define OFF_N4B  (OFF_N2B + 131072ull)
#define OFF_W0B  (OFF_N4B + 131072ull)                           // bf16 W0 [1024*1024]
#define OFF_BAR  (OFF_W0B + 2097152ull)                          // flags[128] u32
#define WS_NEED  (OFF_BAR + 1024ull)

__device__ __forceinline__ unsigned short f2b(float f) {
  union { float f; unsigned u; } v; v.f = f;
  return (unsigned short)((v.u + 0x7FFFu + ((v.u >> 16) & 1u)) >> 16);  // RNE
}
__device__ __forceinline__ float b2f(unsigned short u) {
  union { unsigned u; float f; } v; v.u = ((unsigned)u) << 16;
  return v.f;
}
__device__ __forceinline__ float fast_tanh(float x) {
  return 1.f - 2.f / (__expf(2.f * x) + 1.f);
}
__device__ __forceinline__ float fast_sigm(float x) {
  return 1.f / (1.f + __expf(-x));
}
__device__ __forceinline__ s8v pack8(const float* __restrict__ p) {
  s8v r;
#pragma unroll
  for (int i = 0; i < 8; ++i) r[i] = (short)f2b(p[i]);
  return r;
}

// ---- coherent (L3-direct) helpers: sc0 sc1 = bypass L1+L2 ----
__device__ __forceinline__ void st_sc32(unsigned* p, unsigned v) {
  asm volatile("global_store_dword %0, %1, off sc0 sc1" :: "v"(p), "v"(v) : "memory");
}
__device__ __forceinline__ void st_sc64(unsigned short* p, u2v v) {
  asm volatile("global_store_dwordx2 %0, %1, off sc0 sc1" :: "v"(p), "v"(v) : "memory");
}
__device__ __forceinline__ void wait_vm0() {
  asm volatile("s_waitcnt vmcnt(0)" ::: "memory");
}
__device__ __forceinline__ unsigned ld_sc1_u32(const unsigned* p) {
  unsigned v;
  asm volatile("global_load_dword %0, %1, off sc0 sc1\n\ts_waitcnt vmcnt(0)"
               : "=v"(v) : "v"(p) : "memory");
  return v;
}
__device__ __forceinline__ void st_bf4(unsigned short* p, float x0, float x1, float x2, float x3) {
  u2v v;
  v[0] = (unsigned)f2b(x0) | ((unsigned)f2b(x1) << 16);
  v[1] = (unsigned)f2b(x2) | ((unsigned)f2b(x3) << 16);
  st_sc64(p, v);
}

// 16 coherent dwordx4 loads + waitcnt in ONE asm block (R3 lesson: no window
// where the compiler can spill/copy an in-flight destination register).
#define GL16(B, P) asm volatile(                                        \
  "global_load_dwordx4 %0,  %16, off sc0 sc1\n\t"                       \
  "global_load_dwordx4 %1,  %16, off offset:64 sc0 sc1\n\t"             \
  "global_load_dwordx4 %2,  %16, off offset:128 sc0 sc1\n\t"            \
  "global_load_dwordx4 %3,  %16, off offset:192 sc0 sc1\n\t"            \
  "global_load_dwordx4 %4,  %16, off offset:256 sc0 sc1\n\t"            \
  "global_load_dwordx4 %5,  %16, off offset:320 sc0 sc1\n\t"            \
  "global_load_dwordx4 %6,  %16, off offset:384 sc0 sc1\n\t"            \
  "global_load_dwordx4 %7,  %16, off offset:448 sc0 sc1\n\t"            \
  "global_load_dwordx4 %8,  %16, off offset:512 sc0 sc1\n\t"            \
  "global_load_dwordx4 %9,  %16, off offset:576 sc0 sc1\n\t"            \
  "global_load_dwordx4 %10, %16, off offset:640 sc0 sc1\n\t"            \
  "global_load_dwordx4 %11, %16, off offset:704 sc0 sc1\n\t"            \
  "global_load_dwordx4 %12, %16, off offset:768 sc0 sc1\n\t"            \
  "global_load_dwordx4 %13, %16, off offset:832 sc0 sc1\n\t"            \
  "global_load_dwordx4 %14, %16, off offset:896 sc0 sc1\n\t"            \
  "global_load_dwordx4 %15, %16, off offset:960 sc0 sc1\n\t"            \
  "s_waitcnt vmcnt(0)"                                                  \
  : "=&v"(B[0]), "=&v"(B[1]), "=&v"(B[2]), "=&v"(B[3]),                 \
    "=&v"(B[4]), "=&v"(B[5]), "=&v"(B[6]), "=&v"(B[7]),                 \
    "=&v"(B[8]), "=&v"(B[9]), "=&v"(B[10]), "=&v"(B[11]),               \
    "=&v"(B[12]), "=&v"(B[13]), "=&v"(B[14]), "=&v"(B[15])              \
  : "v"(P) : "memory")

// GL16 + two extra dwordx2 leaf loads (n2,n4), all drained by the same vmcnt(0).
#define GL16L(B, P, V2, P2, V4, P4) asm volatile(                       \
  "global_load_dwordx2 %16, %19, off sc0 sc1\n\t"                       \
  "global_load_dwordx2 %17, %20, off sc0 sc1\n\t"                       \
  "global_load_dwordx4 %0,  %18, off sc0 sc1\n\t"                       \
  "global_load_dwordx4 %1,  %18, off offset:64 sc0 sc1\n\t"             \
  "global_load_dwordx4 %2,  %18, off offset:128 sc0 sc1\n\t"            \
  "global_load_dwordx4 %3,  %18, off offset:192 sc0 sc1\n\t"            \
  "global_load_dwordx4 %4,  %18, off offset:256 sc0 sc1\n\t"            \
  "global_load_dwordx4 %5,  %18, off offset:320 sc0 sc1\n\t"            \
  "global_load_dwordx4 %6,  %18, off offset:384 sc0 sc1\n\t"            \
  "global_load_dwordx4 %7,  %18, off offset:448 sc0 sc1\n\t"            \
  "global_load_dwordx4 %8,  %18, off offset:512 sc0 sc1\n\t"            \
  "global_load_dwordx4 %9,  %18, off offset:576 sc0 sc1\n\t"            \
  "global_load_dwordx4 %10, %18, off offset:640 sc0 sc1\n\t"            \
  "global_load_dwordx4 %11, %18, off offset:704 sc0 sc1\n\t"            \
  "global_load_dwordx4 %12, %18, off offset:768 sc0 sc1\n\t"            \
  "global_load_dwordx4 %13, %18, off offset:832 sc0 sc1\n\t"            \
  "global_load_dwordx4 %14, %18, off offset:896 sc0 sc1\n\t"            \
  "global_load_dwordx4 %15, %18, off offset:960 sc0 sc1\n\t"            \
  "s_waitcnt vmcnt(0)"                                                  \
  : "=&v"(B[0]), "=&v"(B[1]), "=&v"(B[2]), "=&v"(B[3]),                 \
    "=&v"(B[4]), "=&v"(B[5]), "=&v"(B[6]), "=&v"(B[7]),                 \
    "=&v"(B[8]), "=&v"(B[9]), "=&v"(B[10]), "=&v"(B[11]),               \
    "=&v"(B[12]), "=&v"(B[13]), "=&v"(B[14]), "=&v"(B[15]),             \
    "=&v"(V2), "=&v"(V4)                                                \
  : "v"(P), "v"(P2), "v"(P4) : "memory")

// ---------------- W0 fp32 -> bf16 ----------------
__global__ __launch_bounds__(256) void k_cvt(const float* __restrict__ src,
                                             unsigned short* __restrict__ dst) {
  const int i = (blockIdx.x * 256 + threadIdx.x) * 4;
  float4 v = *(const float4*)(src + i);
  ushort4 o; o.x = f2b(v.x); o.y = f2b(v.y); o.z = f2b(v.z); o.w = f2b(v.w);
  *(ushort4*)(dst + i) = o;
}

// ---------------- X0[t] = emb[idx[:,t+1]] @ W0^T + b0 + bs0 ----------------
__global__ __launch_bounds__(256) void k_x0(const float* __restrict__ emb,
                                            const int* __restrict__ ids,
                                            const unsigned short* __restrict__ w0b,
                                            const float* __restrict__ b0,
                                            const float* __restrict__ bs,
                                            float* __restrict__ x0) {
  const int t  = blockIdx.x;            // 0..126
  const int cb = blockIdx.y * 256;      // column base
  const int lane = threadIdx.x & 63, wvv = threadIdx.x >> 6;
  const int lc = lane & 15, lg = lane >> 4;
  const int cw = cb + wvv * 64;
  const float* erow[4];
#pragma unroll
  for (int rt = 0; rt < 4; ++rt)
    erow[rt] = emb + (size_t)ids[(rt * 16 + lc) * 128 + t + 1] * Hdim + lg * 8;
  f4v acc[4][4];
#pragma unroll
  for (int rt = 0; rt < 4; ++rt)
#pragma unroll
    for (int ct = 0; ct < 4; ++ct) acc[rt][ct] = (f4v){0.f, 0.f, 0.f, 0.f};

  for (int ks = 0; ks < 32; ++ks) {
    s8v a[4];
#pragma unroll
    for (int rt = 0; rt < 4; ++rt) a[rt] = pack8(erow[rt] + ks * 32);
#pragma unroll
    for (int ct = 0; ct < 4; ++ct) {
      s8v b = *(const s8v*)(w0b + (size_t)(cw + ct * 16 + lc) * Hdim + ks * 32 + lg * 8);
#pragma unroll
      for (int rt = 0; rt < 4; ++rt)
        acc[rt][ct] = __builtin_amdgcn_mfma_f32_16x16x32_bf16(a[rt], b, acc[rt][ct], 0, 0, 0);
    }
  }
  float* xt = x0 + (size_t)t * (Bsz * Hdim);
#pragma unroll
  for (int ct = 0; ct < 4; ++ct) {
    const int col = cw + ct * 16 + lc;
    const float bias = b0[col] + bs[col];   // bs row 0
#pragma unroll
    for (int rt = 0; rt < 4; ++rt)
#pragma unroll
      for (int j = 0; j < 4; ++j)
        xt[(rt * 16 + lg * 4 + j) * Hdim + col] = acc[rt][ct][j] + bias;
  }
}

// ---------------- grid barrier: coherent flag array, tight spin ----------------
__device__ __forceinline__ void gbar(unsigned* flags, int wg, unsigned phase) {
  __syncthreads();
  const int tid = threadIdx.x;
  if (tid == 0) st_sc32(flags + wg, phase);
  if (tid < 64) {
    const unsigned long long* fp = (const unsigned long long*)flags + tid;
    for (;;) {
      unsigned long long v;
      asm volatile("global_load_dwordx2 %0, %1, off sc0 sc1\n\ts_waitcnt vmcnt(0)"
                   : "=v"(v) : "v"(fp) : "memory");
      int ok = ((unsigned)v >= phase) & ((unsigned)(v >> 32) >= phase);
      if (__all(ok)) break;
    }
  }
  __syncthreads();
}

// one 16-col x 16-row output tile per wave, transposed MFMA:
// D[c, r] = sum_k W[c0+c, k] * act[r, k] via mfma(A=W_frag, B=act_frag).
// lane (lc,lg): batch row = wvv*16+lc, weight cols = c0+lg*4+0..3.
__device__ __forceinline__ f4v slab_mm(const unsigned short* in_b,
                                       const unsigned short* ldw,
                                       int lc, int lg, int wvv) {
  const unsigned short* pa = in_b + (wvv * 16 + lc) * Hdim + lg * 8;
  const unsigned short* br = ldw + lg * 128 + lc * 8;
  f4v a0 = (f4v){0.f, 0.f, 0.f, 0.f}, a1 = (f4v){0.f, 0.f, 0.f, 0.f};
  s8v bb[16];

  GL16(bb, pa);                           // ks 0..15, drained in-block
  __builtin_amdgcn_sched_barrier(0);
#pragma unroll
  for (int k = 0; k < 16; k += 2) {
    s8v w0 = *(const s8v*)(br + k * 512);
    s8v w1 = *(const s8v*)(br + (k + 1) * 512);
    a0 = __builtin_amdgcn_mfma_f32_16x16x32_bf16(w0, bb[k], a0, 0, 0, 0);
    a1 = __builtin_amdgcn_mfma_f32_16x16x32_bf16(w1, bb[k + 1], a1, 0, 0, 0);
  }

  GL16(bb, pa + 512);                     // ks 16..31
  __builtin_amdgcn_sched_barrier(0);
#pragma unroll
  for (int k = 0; k < 16; k += 2) {
    s8v w0 = *(const s8v*)(br + (16 + k) * 512);
    s8v w1 = *(const s8v*)(br + (17 + k) * 512);
    a0 = __builtin_amdgcn_mfma_f32_16x16x32_bf16(w0, bb[k], a0, 0, 0, 0);
    a1 = __builtin_amdgcn_mfma_f32_16x16x32_bf16(w1, bb[k + 1], a1, 0, 0, 0);
  }
  return a0 + a1;
}

// L4 variant: first block also pulls the two leaf dwordx2 (n2,n4), same drain.
__device__ __forceinline__ f4v slab_mm_l4(const unsigned short* in_b,
                                          const unsigned short* ldw,
                                          int lc, int lg, int wvv,
                                          const unsigned short* p2, u2v* v2o,
                                          const unsigned short* p4, u2v* v4o) {
  const unsigned short* pa = in_b + (wvv * 16 + lc) * Hdim + lg * 8;
  const unsigned short* br = ldw + lg * 128 + lc * 8;
  f4v a0 = (f4v){0.f, 0.f, 0.f, 0.f}, a1 = (f4v){0.f, 0.f, 0.f, 0.f};
  s8v bb[16];
  u2v v2, v4;

  GL16L(bb, pa, v2, p2, v4, p4);
  __builtin_amdgcn_sched_barrier(0);
#pragma unroll
  for (int k = 0; k < 16; k += 2) {
    s8v w0 = *(const s8v*)(br + k * 512);
    s8v w1 = *(const s8v*)(br + (k + 1) * 512);
    a0 = __builtin_amdgcn_mfma_f32_16x16x32_bf16(w0, bb[k], a0, 0, 0, 0);
    a1 = __builtin_amdgcn_mfma_f32_16x16x32_bf16(w1, bb[k + 1], a1, 0, 0, 0);
  }

  GL16(bb, pa + 512);
  __builtin_amdgcn_sched_barrier(0);
#pragma unroll
  for (int k = 0; k < 16; k += 2) {
    s8v w0 = *(const s8v*)(br + (16 + k) * 512);
    s8v w1 = *(const s8v*)(br + (17 + k) * 512);
    a0 = __builtin_amdgcn_mfma_f32_16x16x32_bf16(w0, bb[k], a0, 0, 0, 0);
    a1 = __builtin_amdgcn_mfma_f32_16x16x32_bf16(w1, bb[k + 1], a1, 0, 0, 0);
  }
  *v2o = v2; *v4o = v4;
  return a0 + a1;
}

// ---------------- persistent scan: 127 steps x 4 levels + clock heaters ----------------
__global__ __launch_bounds__(256, 1) void k_scan(const float* __restrict__ Ws,
                                                 const float* __restrict__ bs,
                                                 const float* __restrict__ h_in,
                                                 const float* __restrict__ Wsum,
                                                 const float* __restrict__ bsum,
                                                 const float* __restrict__ act,
                                                 char* __restrict__ ws) {
  const int tid = threadIdx.x;
  unsigned* flags = (unsigned*)(ws + OFF_BAR);

  // ---- heater WGs: keep SMU at high DPM with dependent-FMA chains ----
  if (blockIdx.x >= NWG) {
    float a = 1.f + (float)(tid & 63) * 1e-6f;
    const float bm = 1.0000001f, cm = 1e-7f;
    for (int it = 0; it < (1 << 14); ++it) {      // safety cap ~ tens of ms
#pragma unroll
      for (int i = 0; i < 256; ++i) a = __builtin_fmaf(a, bm, cm);
      if ((it & 3) == 0 && ld_sc1_u32(flags) >= FINPH) break;
    }
    asm volatile("" :: "v"(a));                   // keep chain live (rule #17)
    return;
  }

  __shared__ unsigned short lds[3 * 16384];   // 96 KiB: three [16 cols x 1024 k] slices
  const int w = blockIdx.x;
  const int half = w >> 6;          // 0: {M0,M1,M3}, 1: {M2,M4,M5}
  const int c0 = (w & 63) * 16;
  const int lane = tid & 63, wvv = tid >> 6;
  const int lc = lane & 15, lg = lane >> 4;

  unsigned short* hb  = (unsigned short*)(ws + OFF_HB);
  unsigned short* n1b = (unsigned short*)(ws + OFF_N1);
  unsigned short* n3b = (unsigned short*)(ws + OFF_N3);
  unsigned short* n5b = (unsigned short*)(ws + OFF_N5);
  unsigned short* n2b = (unsigned short*)(ws + OFF_N2B);
  unsigned short* n4b = (unsigned short*)(ws + OFF_N4B);
  const float* x0 = (const float*)(ws + OFF_X0);

  // load 3 weight slices (fp32 global -> bf16 LDS, tiled [k/8][16][8])
  const int m0 = (half == 0) ? 0 : 2;
  const int m1 = (half == 0) ? 1 : 4;
  const int m2 = (half == 0) ? 3 : 5;
  const int mats[3] = {m0, m1, m2};
#pragma unroll
  for (int s = 0; s < 3; ++s) {
    const float* msrc = Ws + (size_t)mats[s] * (Hdim * Hdim);
    unsigned short* dst = lds + s * 16384;
    for (int i = tid; i < 4096; i += NTHR) {
      const int c = i >> 8, k4 = i & 255;
      float4 v = *(const float4*)(msrc + (size_t)(c0 + c) * Hdim + k4 * 4);
      ushort4 o; o.x = f2b(v.x); o.y = f2b(v.y); o.z = f2b(v.z); o.w = f2b(v.w);
      *(ushort4*)(dst + ((k4 >> 1) * 16 + c) * 8 + (k4 & 1) * 4) = o;
    }
  }
  // per-lane biases: 4 consecutive cols (c0 + lg*4 + 0..3) per matrix
  float4 bias_a, bias_b, bias_c = (float4){0.f, 0.f, 0.f, 0.f};
  if (half == 0) {
    bias_a = *(const float4*)(bs + 1 * Hdim + c0 + lg * 4);
    bias_b = *(const float4*)(bs + 3 * Hdim + c0 + lg * 4);
  } else {
    bias_a = *(const float4*)(bs + 2 * Hdim + c0 + lg * 4);
    bias_b = *(const float4*)(bs + 4 * Hdim + c0 + lg * 4);
    bias_c = *(const float4*)(bs + 5 * Hdim + c0 + lg * 4);
  }

  // softmax combine weights over nodes {2,4,6} -> weight rows {1,3,5}
  float cw[3];
#pragma unroll
  for (int j = 0; j < 3; ++j) {
    const int i = 2 * j + 1;
    float s = bsum[i];
    for (int a2 = 0; a2 < 12; ++a2) s += Wsum[i * 12 + a2] * act[a2];
    cw[j] = s;
  }
  {
    float m = fmaxf(cw[0], fmaxf(cw[1], cw[2]));
    float e0 = __expf(cw[0] - m), e1 = __expf(cw[1] - m), e2 = __expf(cw[2] - m);
    float inv = 1.f / (e0 + e1 + e2);
    cw[0] = e0 * inv; cw[1] = e1 * inv; cw[2] = e2 * inv;
  }

  // initial h fp32 -> bf16 (coherent)
  {
    const int base = w * 512 + tid * 2;
    unsigned pk = (unsigned)f2b(h_in[base]) | ((unsigned)f2b(h_in[base + 1]) << 16);
    st_sc32((unsigned*)(hb + base), pk);
    wait_vm0();
  }

  unsigned phase = 1;
  gbar(flags, w, phase++);

  const int row = wvv * 16 + lc;          // this lane's batch row
  const int colb = c0 + lg * 4;           // this lane's 4 output cols

  for (int t = 0; t < TST; ++t) {
    // L1: n1 = tanh(h @ M0^T + X0[t])   (X0 already contains b0+bs0)
    if (half == 0) {
      // hoist x0 read: plain cached load, drains inside slab_mm's vmcnt(0)
      float4 xv = *(const float4*)(x0 + (size_t)t * (Bsz * Hdim) + row * Hdim + colb);
      f4v acc = slab_mm(hb, lds, lc, lg, wvv);
      st_bf4(n1b + row * Hdim + colb,
             fast_tanh(acc[0] + xv.x), fast_tanh(acc[1] + xv.y),
             fast_tanh(acc[2] + xv.z), fast_tanh(acc[3] + xv.w));
      wait_vm0();
    }
    gbar(flags, w, phase++);

    // L2: n2 = relu(n1@M1^T+b1) [half0] ; n3 = sigmoid(n1@M2^T+b2) [half1]
    if (half == 0) {
      f4v acc = slab_mm(n1b, lds + 16384, lc, lg, wvv);
      st_bf4(n2b + row * Hdim + colb,
             fmaxf(acc[0] + bias_a.x, 0.f), fmaxf(acc[1] + bias_a.y, 0.f),
             fmaxf(acc[2] + bias_a.z, 0.f), fmaxf(acc[3] + bias_a.w, 0.f));
    } else {
      f4v acc = slab_mm(n1b, lds, lc, lg, wvv);
      st_bf4(n3b + row * Hdim + colb,
             fast_sigm(acc[0] + bias_a.x), fast_sigm(acc[1] + bias_a.y),
             fast_sigm(acc[2] + bias_a.z), fast_sigm(acc[3] + bias_a.w));
    }
    wait_vm0();
    gbar(flags, w, phase++);

    // L3: n4 = tanh(n3@M3^T+b3) [half0] ; n5 = relu(n3@M4^T+b4) [half1]
    if (half == 0) {
      f4v acc = slab_mm(n3b, lds + 32768, lc, lg, wvv);
      st_bf4(n4b + row * Hdim + colb,
             fast_tanh(acc[0] + bias_b.x), fast_tanh(acc[1] + bias_b.y),
             fast_tanh(acc[2] + bias_b.z), fast_tanh(acc[3] + bias_b.w));
    } else {
      f4v acc = slab_mm(n3b, lds + 16384, lc, lg, wvv);
      st_bf4(n5b + row * Hdim + colb,
             fmaxf(acc[0] + bias_b.x, 0.f), fmaxf(acc[1] + bias_b.y, 0.f),
             fmaxf(acc[2] + bias_b.z, 0.f), fmaxf(acc[3] + bias_b.w, 0.f));
    }
    wait_vm0();
    gbar(flags, w, phase++);

    // L4: n6 = tanh(n5@M5^T+b5); h = cw0*n2 + cw1*n4 + cw2*n6  [half1]
    if (half == 1) {
      u2v v2, v4;
      f4v acc = slab_mm_l4(n5b, lds + 32768, lc, lg, wvv,
                           n2b + row * Hdim + colb, &v2,
                           n4b + row * Hdim + colb, &v4);
      float hv[4];
#pragma unroll
      for (int j = 0; j < 4; ++j) {
        const float v6 = fast_tanh(acc[j] + ((const float*)&bias_c)[j]);
        const float f2 = b2f((unsigned short)(v2[j >> 1] >> ((j & 1) * 16)));
        const float f4 = b2f((unsigned short)(v4[j >> 1] >> ((j & 1) * 16)));
        hv[j] = cw[0] * f2 + cw[1] * f4 + cw[2] * v6;
      }
      st_bf4(hb + row * Hdim + colb, hv[0], hv[1], hv[2], hv[3]);
      wait_vm0();
    }
    gbar(flags, w, phase++);
  }
}

// ---------------- epilogue: out = h @ W_out^T + b_out ----------------
__global__ __launch_bounds__(256) void k_out(const unsigned short* __restrict__ hb,
                                             const float* __restrict__ wout,
                                             const float* __restrict__ bout,
                                             float* __restrict__ out) {
  const int cb = blockIdx.x * 128;
  const int lane = threadIdx.x & 63, wvv = threadIdx.x >> 6;
  const int lc = lane & 15, lg = lane >> 4;
  const int cw = cb + wvv * 32;
  f4v acc[4][2];
#pragma unroll
  for (int rt = 0; rt < 4; ++rt)
#pragma unroll
    for (int ct = 0; ct < 2; ++ct) acc[rt][ct] = (f4v){0.f, 0.f, 0.f, 0.f};

  for (int ks = 0; ks < 32; ++ks) {
    s8v a[4];
#pragma unroll
    for (int rt = 0; rt < 4; ++rt)
      a[rt] = *(const s8v*)(hb + (rt * 16 + lc) * Hdim + ks * 32 + lg * 8);
#pragma unroll
    for (int ct = 0; ct < 2; ++ct) {
      const int col = cw + ct * 16 + lc;
      const int cs = col < NCLS ? col : NCLS - 1;
      s8v b = pack8(wout + (size_t)cs * Hdim + ks * 32 + lg * 8);
#pragma unroll
      for (int rt = 0; rt < 4; ++rt)
        acc[rt][ct] = __builtin_amdgcn_mfma_f32_16x16x32_bf16(a[rt], b, acc[rt][ct], 0, 0, 0);
    }
  }
#pragma unroll
  for (int ct = 0; ct < 2; ++ct) {
    const int col = cw + ct * 16 + lc;
    if (col < NCLS) {
      const float bias = bout[col];
#pragma unroll
      for (int rt = 0; rt < 4; ++rt)
#pragma unroll
        for (int j = 0; j < 4; ++j)
          out[(size_t)(rt * 16 + lg * 4 + j) * NCLS + col] = acc[rt][ct][j] + bias;
    }
  }
}

extern "C" void kernel_launch(void* const* d_in, const int* in_sizes, int n_in,
                              void* d_out, int out_size, void* d_ws, size_t ws_size,
                              hipStream_t stream) {
  (void)in_sizes; (void)n_in; (void)out_size;
  if (ws_size < WS_NEED) return;

  const float* emb  = (const float*)d_in[0];
  const float* h0   = (const float*)d_in[1];
  const int*   ids  = (const int*)d_in[2];
  const float* W0   = (const float*)d_in[3];
  const float* b0   = (const float*)d_in[4];
  const float* Ws   = (const float*)d_in[5];
  const float* bsp  = (const float*)d_in[6];
  const float* Wout = (const float*)d_in[7];
  const float* bout = (const float*)d_in[8];
  const float* Wsum = (const float*)d_in[9];
  const float* bsum = (const float*)d_in[10];
  const float* actv = (const float*)d_in[11];
  char* ws  = (char*)d_ws;
  float* out = (float*)d_out;

  hipMemsetAsync(ws + OFF_BAR, 0, 1024, stream);                      // flags
  k_cvt<<<1024, 256, 0, stream>>>(W0, (unsigned short*)(ws + OFF_W0B));
  k_x0<<<dim3(TST, 4), 256, 0, stream>>>(emb, ids, (const unsigned short*)(ws + OFF_W0B),
                                         b0, bsp, (float*)(ws + OFF_X0));

  void* args[] = { (void*)&Ws, (void*)&bsp, (void*)&h0, (void*)&Wsum,
                   (void*)&bsum, (void*)&actv, (void*)&ws };
  hipLaunchCooperativeKernel((void*)k_scan, dim3(NGRID), dim3(NTHR), args, 0, stream);

  k_out<<<391, 256, 0, stream>>>((const unsigned short*)(ws + OFF_HB), Wout, bout, out);
}